// Round 6
// baseline (465.605 us; speedup 1.0000x reference)
//
#include <hip/hip_runtime.h>
#include <hip/hip_bf16.h>

typedef short short8 __attribute__((ext_vector_type(8)));
typedef short short4_t __attribute__((ext_vector_type(4)));
typedef float floatx4 __attribute__((ext_vector_type(4)));

#define DEVI __device__ __forceinline__

// Dims: B=4, T=4096, D=256, E=12 (4x k5, 4x k9, 4x k17), 16384 tokens.
// fp32 in/out; MFMA operands bf16.
//
// prep:  2257 blocks x 256: bid<2048 x->bf16 convert; else weight transposes.
// fused: 512 blocks x 256 (4 waves, homogeneous). BM=32 tokens.
//        In-kernel MFMA router. Chunk = half-expert (128 k) + bias chunk.
//        conv reads bf16 x from global (L2-hot, XCD swizzle). R2-proven
//        register shape: acc[2][4], distance-1 B prefetch. No spill target.
//
// ws: projWT bf16 [12][256f][256d] @ 0         (1,572,864)
//     outWT  bf16 [256f][256k]     @ 1,572,864 (131,072)
//     projbT bf16 [256n][32k]      @ 1,703,936 (16,384)  (k>=12 zero)
//     rWT    bf16 [16e][256d]      @ 1,720,320 (8,192)   (e>=12 zero)
//     xbf    bf16 [16384][256]     @ 1,728,512 (8,388,608)

DEVI float bf2f(__hip_bfloat16 v) { return __bfloat162float(v); }
DEVI __hip_bfloat16 f2bf(float v) { return __float2bfloat16(v); }
DEVI unsigned short bfbits(float v) { __hip_bfloat16 b = f2bf(v); return *(unsigned short*)&b; }

// ---------------------------------------------------------------- prep ----
__global__ __launch_bounds__(256) void prep_kernel(
    const float* __restrict__ x,       // [16384][256]
    const float* __restrict__ rW,      // [256][12]
    const float* __restrict__ projW,   // [12][256d][256f]
    const float* __restrict__ outW,    // [256k][256f]
    const float* __restrict__ projb,   // [12][256]
    __hip_bfloat16* __restrict__ xbf,
    __hip_bfloat16* __restrict__ projWT,
    __hip_bfloat16* __restrict__ outWT,
    __hip_bfloat16* __restrict__ projbT,
    __hip_bfloat16* __restrict__ rWT)
{
    __shared__ __align__(16) __hip_bfloat16 Tt[64 * 72];
    const int bid = blockIdx.x;
    const int tid = threadIdx.x;

    if (bid < 2048) {              // x -> bf16, 2048 els/block
        size_t base = (size_t)bid * 2048 + (size_t)tid * 8;
        float4 f0 = *(const float4*)(x + base);
        float4 f1 = *(const float4*)(x + base + 4);
        short8 o;
        o[0] = (short)bfbits(f0.x); o[1] = (short)bfbits(f0.y);
        o[2] = (short)bfbits(f0.z); o[3] = (short)bfbits(f0.w);
        o[4] = (short)bfbits(f1.x); o[5] = (short)bfbits(f1.y);
        o[6] = (short)bfbits(f1.z); o[7] = (short)bfbits(f1.w);
        *(short8*)(xbf + base) = o;
        return;
    }

    const int b2 = bid - 2048;
    if (b2 == 208) {               // projbT + rWT
#pragma unroll
        for (int k = 0; k < 32; k++)
            projbT[tid * 32 + k] = (k < 12) ? f2bf(projb[k * 256 + tid]) : f2bf(0.f);
#pragma unroll
        for (int e = 0; e < 16; e++)
            rWT[e * 256 + tid] = (e < 12) ? f2bf(rW[tid * 12 + e]) : f2bf(0.f);
        return;
    }
    const float* src;
    __hip_bfloat16* dst;
    if (b2 < 192) {
        int e = b2 >> 4, ti = (b2 & 15) >> 2, tj = b2 & 3;
        src = projW + (e << 16) + (ti * 64) * 256 + tj * 64;
        dst = projWT + (e << 16) + (tj * 64) * 256 + ti * 64;
    } else {
        int b3 = b2 - 192, ti = b3 >> 2, tj = b3 & 3;
        src = outW + (ti * 64) * 256 + tj * 64;
        dst = outWT + (tj * 64) * 256 + ti * 64;
    }
#pragma unroll
    for (int i = 0; i < 4; i++) {
        int r = i * 16 + (tid >> 4);
        int c4 = (tid & 15) * 4;
        float4 f = *(const float4*)(src + r * 256 + c4);
        Tt[(c4 + 0) * 72 + r] = f2bf(f.x);
        Tt[(c4 + 1) * 72 + r] = f2bf(f.y);
        Tt[(c4 + 2) * 72 + r] = f2bf(f.z);
        Tt[(c4 + 3) * 72 + r] = f2bf(f.w);
    }
    __syncthreads();
#pragma unroll
    for (int i = 0; i < 2; i++) {
        int c = i * 32 + (tid >> 3);
        int r8 = (tid & 7) * 8;
        *(short8*)(dst + c * 256 + r8) = *(const short8*)(Tt + c * 72 + r8);
    }
}

// --------------------------------------------------------------- fused ----
// LDS (20,480 B):
//   As    bf16 2 x [32][136] @ 0      (17,408)  A chunk dbuf
//   wts_s f32  [32][12]      @ 17,408 ( 1,536)
//   psum  f32  [32][5]       @ 18,944 (   640)
//   psq   f32  [32][5]       @ 19,584 (   640)
//   muA   f32  [32]          @ 20,224   rsA f32 [32] @ 20,352
//   normed bf16 [32][264]    @ 0      (16,896)  aliases As after chunk loop

template<int K>
DEVI void conv_col(const float* __restrict__ cw,          // [K][256] expert
                   const __hip_bfloat16* __restrict__ xrow,
                   int t0, int tloc,
                   const float* __restrict__ wts_s, int e,
                   __hip_bfloat16* __restrict__ dst, int d_l, int d_g)
{
    float c[K];
#pragma unroll
    for (int j = 0; j < K; j++) c[j] = cw[j * 256 + d_g];
    float w[K - 1];
#pragma unroll
    for (int i = 0; i < K - 1; i++) {
        int tt = t0 + tloc - (K - 1) + i;
        w[i] = (tt >= 0) ? bf2f(xrow[(size_t)tt * 256 + d_g]) : 0.f;
    }
#pragma unroll
    for (int t = 0; t < 16; t++) {
        float nv = bf2f(xrow[(size_t)(t0 + tloc + t) * 256 + d_g]);
        float s = nv * c[K - 1];
#pragma unroll
        for (int i = 0; i < K - 1; i++) s += w[i] * c[i];
        dst[(tloc + t) * 136 + d_l] = f2bf(s * wts_s[(tloc + t) * 12 + e]);
#pragma unroll
        for (int i = 0; i + 1 < K - 1; i++) w[i] = w[i + 1];
        w[K - 2] = nv;
    }
}

// M=32 x N=64(wave slice) x K=NKS*32; distance-1 B/A prefetch (R2-proven)
template<int NKS>
DEVI void gemm_tile(const __hip_bfloat16* __restrict__ A, int astride,
                    const __hip_bfloat16* __restrict__ Bg, int bstride,
                    floatx4 (&acc)[2][4], int l16, int quad, int nsl)
{
    const __hip_bfloat16* a0p = A + l16 * astride + quad * 8;
    const __hip_bfloat16* a1p = a0p + 16 * astride;
    const __hip_bfloat16* bp  = Bg + (nsl + l16) * bstride + quad * 8;
    short8 a0 = *(const short8*)(a0p);
    short8 a1 = *(const short8*)(a1p);
    short8 b[4];
#pragma unroll
    for (int nt = 0; nt < 4; nt++)
        b[nt] = *(const short8*)(bp + nt * 16 * bstride);
#pragma unroll
    for (int ks = 0; ks < NKS; ks++) {
        short8 na0, na1, nb[4];
        if (ks < NKS - 1) {
            na0 = *(const short8*)(a0p + (ks + 1) * 32);
            na1 = *(const short8*)(a1p + (ks + 1) * 32);
#pragma unroll
            for (int nt = 0; nt < 4; nt++)
                nb[nt] = *(const short8*)(bp + nt * 16 * bstride + (ks + 1) * 32);
        }
#pragma unroll
        for (int nt = 0; nt < 4; nt++) {
            acc[0][nt] = __builtin_amdgcn_mfma_f32_16x16x32_bf16(a0, b[nt], acc[0][nt], 0, 0, 0);
            acc[1][nt] = __builtin_amdgcn_mfma_f32_16x16x32_bf16(a1, b[nt], acc[1][nt], 0, 0, 0);
        }
        if (ks < NKS - 1) {
            a0 = na0; a1 = na1;
#pragma unroll
            for (int nt = 0; nt < 4; nt++) b[nt] = nb[nt];
        }
    }
}

__global__ __launch_bounds__(256, 5) void fused_kernel(
    const __hip_bfloat16* __restrict__ xbf,
    const float* __restrict__ ck5, const float* __restrict__ ck9,
    const float* __restrict__ ck17,
    const float* __restrict__ rb,      // [12]
    const float* __restrict__ gmm, const float* __restrict__ bta,
    const float* __restrict__ outb,
    const __hip_bfloat16* __restrict__ projWT,
    const __hip_bfloat16* __restrict__ outWT,
    const __hip_bfloat16* __restrict__ projbT,
    const __hip_bfloat16* __restrict__ rWT,
    float* __restrict__ out)
{
    __shared__ __align__(16) char smem[20480];
    __hip_bfloat16* As = (__hip_bfloat16*)smem;       // 2 x [32][136]
    __hip_bfloat16* normed = (__hip_bfloat16*)smem;   // [32][264] later
    float* wts_s = (float*)(smem + 17408);
    float* psum  = (float*)(smem + 18944);
    float* psq   = (float*)(smem + 19584);
    float* muA   = (float*)(smem + 20224);
    float* rsA   = (float*)(smem + 20352);

    const int tid  = threadIdx.x;
    const int wave = tid >> 6;
    const int lane = tid & 63;
    const int quad = lane >> 4;
    const int l16  = lane & 15;
    const int nsl  = wave * 64;                // n-slice base
    // XCD-contiguous swizzle: XCD k (blockIdx%8) gets tiles k*64..k*64+63
    const int tile = (blockIdx.x & 7) * 64 + (blockIdx.x >> 3);
    const int m0   = tile * 32;
    const int bb   = m0 >> 12;
    const int t0   = m0 & 4095;
    const __hip_bfloat16* xrow = xbf + (size_t)bb * 4096 * 256;

    // ---- router (waves 0,1; 16 tokens each): MFMA + softmax ----
    if (wave < 2) {
        floatx4 ra = {0.f, 0.f, 0.f, 0.f};
        const __hip_bfloat16* ap = xbf + (size_t)(m0 + wave * 16 + l16) * 256 + quad * 8;
        const __hip_bfloat16* bp = rWT + l16 * 256 + quad * 8;
#pragma unroll
        for (int kk = 0; kk < 256; kk += 32)
            ra = __builtin_amdgcn_mfma_f32_16x16x32_bf16(
                *(const short8*)(ap + kk), *(const short8*)(bp + kk), ra, 0, 0, 0);
        float rbv = (l16 < 12) ? rb[l16] : 0.f;
#pragma unroll
        for (int r = 0; r < 4; r++) {
            float v = (l16 < 12) ? (ra[r] + rbv) : -1e30f;
            float mx = v;
            mx = fmaxf(mx, __shfl_xor(mx, 1));
            mx = fmaxf(mx, __shfl_xor(mx, 2));
            mx = fmaxf(mx, __shfl_xor(mx, 4));
            mx = fmaxf(mx, __shfl_xor(mx, 8));
            float ex = (l16 < 12) ? __expf(v - mx) : 0.f;
            float sm = ex;
            sm += __shfl_xor(sm, 1);
            sm += __shfl_xor(sm, 2);
            sm += __shfl_xor(sm, 4);
            sm += __shfl_xor(sm, 8);
            if (l16 < 12) wts_s[(wave * 16 + quad * 4 + r) * 12 + l16] = ex / sm;
        }
    }
    __syncthreads();

    // producer chunk: c<24: e=c>>1, h=c&1; c==24: bias chunk (A = router wts)
    auto produce = [&](int c) {
        __hip_bfloat16* dst = As + (c & 1) * (32 * 136);
        if (c == 24) {
            int t = tid >> 3, k4 = (tid & 7) * 4;
            short4_t v;
#pragma unroll
            for (int j = 0; j < 4; j++) {
                int k = k4 + j;
                v[j] = (k < 12) ? (short)bfbits(wts_s[t * 12 + k]) : (short)0;
            }
            *(short4_t*)(dst + t * 136 + k4) = v;
        } else {
            int e = c >> 1, h = c & 1;
            int d_l = tid & 127, tloc = (tid >> 7) * 16;
            int d_g = h * 128 + d_l;
            if (e < 4)
                conv_col<5>(ck5 + e * 5 * 256, xrow, t0, tloc, wts_s, e, dst, d_l, d_g);
            else if (e < 8)
                conv_col<9>(ck9 + (e - 4) * 9 * 256, xrow, t0, tloc, wts_s, e, dst, d_l, d_g);
            else
                conv_col<17>(ck17 + (e - 8) * 17 * 256, xrow, t0, tloc, wts_s, e, dst, d_l, d_g);
        }
    };

    floatx4 acc[2][4];
#pragma unroll
    for (int i = 0; i < 2; i++)
#pragma unroll
        for (int j = 0; j < 4; j++) acc[i][j] = {0.f, 0.f, 0.f, 0.f};

    produce(0);
    __syncthreads();

#pragma unroll 1
    for (int c = 0; c < 25; c++) {
        if (c < 24) {
            produce(c + 1);
            int e = c >> 1, h = c & 1;
            gemm_tile<4>(As + (c & 1) * (32 * 136), 136,
                         projWT + (e << 16) + h * 128, 256, acc, l16, quad, nsl);
        } else {
            gemm_tile<1>(As + (c & 1) * (32 * 136), 136,
                         projbT, 32, acc, l16, quad, nsl);
        }
        __syncthreads();
    }

    // ---- LN stats from accumulators (exact fp32) ----
    {
        float s[8], s2[8];
#pragma unroll
        for (int mf = 0; mf < 2; mf++)
#pragma unroll
            for (int r = 0; r < 4; r++) {
                int i = mf * 4 + r;
                float v = 0.f, q = 0.f;
#pragma unroll
                for (int nt = 0; nt < 4; nt++) {
                    float a = acc[mf][nt][r];
                    v += a; q += a * a;
                }
                s[i] = v; s2[i] = q;
            }
#pragma unroll
        for (int m = 1; m <= 8; m <<= 1)
#pragma unroll
            for (int i = 0; i < 8; i++) {
                s[i]  += __shfl_xor(s[i], m);
                s2[i] += __shfl_xor(s2[i], m);
            }
#pragma unroll
        for (int i = 0; i < 8; i++)
            if (l16 == i) {
                int row = (i >> 2) * 16 + quad * 4 + (i & 3);
                psum[row * 5 + wave] = s[i];
                psq[row * 5 + wave]  = s2[i];
            }
    }
    __syncthreads();
    if (tid < 32) {
        float ss = 0.f, qq = 0.f;
#pragma unroll
        for (int p = 0; p < 4; p++) { ss += psum[tid * 5 + p]; qq += psq[tid * 5 + p]; }
        float mu = ss * 0.00390625f;
        float var = fmaxf(qq * 0.00390625f - mu * mu, 0.f);
        muA[tid] = mu;
        rsA[tid] = rsqrtf(var + 1e-5f);
    }
    __syncthreads();

    // ---- normalize acc -> normed bf16 [32][264] ----
#pragma unroll
    for (int nt = 0; nt < 4; nt++) {
        int col = nsl + nt * 16 + l16;
        float g = gmm[col], bt = bta[col];
#pragma unroll
        for (int mf = 0; mf < 2; mf++)
#pragma unroll
            for (int r = 0; r < 4; r++) {
                int row = mf * 16 + quad * 4 + r;
                normed[row * 264 + col] =
                    f2bf((acc[mf][nt][r] - muA[row]) * rsA[row] * g + bt);
            }
    }
    __syncthreads();

    // ---- out = normed @ out_W + out_b ----
    floatx4 acc2[2][4];
#pragma unroll
    for (int i = 0; i < 2; i++)
#pragma unroll
        for (int j = 0; j < 4; j++) acc2[i][j] = {0.f, 0.f, 0.f, 0.f};
    gemm_tile<8>(normed, 264, outWT, 256, acc2, l16, quad, nsl);

    float* op = out + (size_t)m0 * 256;
#pragma unroll
    for (int nt = 0; nt < 4; nt++) {
        int col = nsl + nt * 16 + l16;
        float ob = outb[col];
#pragma unroll
        for (int mf = 0; mf < 2; mf++)
#pragma unroll
            for (int r = 0; r < 4; r++) {
                int row = mf * 16 + quad * 4 + r;
                op[row * 256 + col] = acc2[mf][nt][r] + ob;
            }
    }
}

// -------------------------------------------------------------- launch ----
extern "C" void kernel_launch(void* const* d_in, const int* in_sizes, int n_in,
                              void* d_out, int out_size, void* d_ws, size_t ws_size,
                              hipStream_t stream)
{
    (void)in_sizes; (void)n_in; (void)out_size; (void)ws_size;
    const float* x     = (const float*)d_in[0];
    const float* ck5   = (const float*)d_in[1];
    const float* ck9   = (const float*)d_in[2];
    const float* ck17  = (const float*)d_in[3];
    const float* projW = (const float*)d_in[4];
    const float* projb = (const float*)d_in[5];
    const float* rW    = (const float*)d_in[6];
    const float* rb    = (const float*)d_in[7];
    const float* outW  = (const float*)d_in[8];
    const float* outb  = (const float*)d_in[9];
    const float* gmm   = (const float*)d_in[10];
    const float* bta   = (const float*)d_in[11];

    __hip_bfloat16* projWT = (__hip_bfloat16*)d_ws;
    __hip_bfloat16* outWT  = (__hip_bfloat16*)((char*)d_ws + 1572864);
    __hip_bfloat16* projbT = (__hip_bfloat16*)((char*)d_ws + 1703936);
    __hip_bfloat16* rWT    = (__hip_bfloat16*)((char*)d_ws + 1720320);
    __hip_bfloat16* xbf    = (__hip_bfloat16*)((char*)d_ws + 1728512);

    prep_kernel<<<dim3(2257), dim3(256), 0, stream>>>(
        x, rW, projW, outW, projb, xbf, projWT, outWT, projbT, rWT);
    fused_kernel<<<dim3(512), dim3(256), 0, stream>>>(
        xbf, ck5, ck9, ck17, rb, gmm, bta, outb,
        projWT, outWT, projbT, rWT, (float*)d_out);
}

// Round 7
// 213.355 us; speedup vs baseline: 2.1823x; 2.1823x over previous
//
#include <hip/hip_runtime.h>
#include <hip/hip_bf16.h>

typedef short short8 __attribute__((ext_vector_type(8)));
typedef short short4_t __attribute__((ext_vector_type(4)));
typedef float floatx4 __attribute__((ext_vector_type(4)));

#define DEVI __device__ __forceinline__

// Dims: B=4, T=4096, D=256, E=12 (4x k5, 4x k9, 4x k17), 16384 tokens.
// fp32 in/out; MFMA operands bf16.
//
// fused: 512 blocks x 256 threads (R2-proven shape, launch_bounds (256,2)).
//   BM=32. x staged to LDS once (fp32->bf16). Chunk = half-expert (K=128),
//   As double-buffered. Bias folded as 25th MFMA chunk; LN from accumulators.
//
// ws: projWT bf16 [12][256f][256d] @ 0         (1,572,864)
//     outWT  bf16 [256f][256k]     @ 1,572,864 (131,072)
//     projbT bf16 [256n][32k]      @ 1,703,936 (16,384)  (k>=12 zero)
//     rWT    bf16 [16e][256d]      @ 1,720,320 (8,192)   (e>=12 zero)

DEVI float bf2f(__hip_bfloat16 v) { return __bfloat162float(v); }
DEVI __hip_bfloat16 f2bf(float v) { return __float2bfloat16(v); }
DEVI unsigned short bfbits(float v) { __hip_bfloat16 b = f2bf(v); return *(unsigned short*)&b; }

// ---------------------------------------------------------------- prep ----
// 209 blocks: 0..191 projW 64x64 transpose tiles, 192..207 outW, 208 misc.
__global__ __launch_bounds__(256) void prep_kernel(
    const float* __restrict__ rW,      // [256][12]
    const float* __restrict__ projW,   // [12][256d][256f]
    const float* __restrict__ outW,    // [256k][256f]
    const float* __restrict__ projb,   // [12][256]
    __hip_bfloat16* __restrict__ projWT,
    __hip_bfloat16* __restrict__ outWT,
    __hip_bfloat16* __restrict__ projbT,
    __hip_bfloat16* __restrict__ rWT)
{
    __shared__ __align__(16) __hip_bfloat16 Tt[64 * 72];
    const int bid = blockIdx.x;
    const int tid = threadIdx.x;

    if (bid == 208) {
#pragma unroll
        for (int k = 0; k < 32; k++)
            projbT[tid * 32 + k] = (k < 12) ? f2bf(projb[k * 256 + tid]) : f2bf(0.f);
#pragma unroll
        for (int e = 0; e < 16; e++)
            rWT[e * 256 + tid] = (e < 12) ? f2bf(rW[tid * 12 + e]) : f2bf(0.f);
        return;
    }
    const float* src;
    __hip_bfloat16* dst;
    if (bid < 192) {
        int e = bid >> 4, ti = (bid & 15) >> 2, tj = bid & 3;
        src = projW + (e << 16) + (ti * 64) * 256 + tj * 64;
        dst = projWT + (e << 16) + (tj * 64) * 256 + ti * 64;
    } else {
        int b3 = bid - 192, ti = b3 >> 2, tj = b3 & 3;
        src = outW + (ti * 64) * 256 + tj * 64;
        dst = outWT + (tj * 64) * 256 + ti * 64;
    }
#pragma unroll
    for (int i = 0; i < 4; i++) {
        int r = i * 16 + (tid >> 4);
        int c4 = (tid & 15) * 4;
        float4 f = *(const float4*)(src + r * 256 + c4);
        Tt[(c4 + 0) * 72 + r] = f2bf(f.x);
        Tt[(c4 + 1) * 72 + r] = f2bf(f.y);
        Tt[(c4 + 2) * 72 + r] = f2bf(f.z);
        Tt[(c4 + 3) * 72 + r] = f2bf(f.w);
    }
    __syncthreads();
#pragma unroll
    for (int i = 0; i < 2; i++) {
        int c = i * 32 + (tid >> 3);
        int r8 = (tid & 7) * 8;
        *(short8*)(dst + c * 256 + r8) = *(const short8*)(Tt + c * 72 + r8);
    }
}

// --------------------------------------------------------------- fused ----
// LDS (46,592 B):
//   xs    bf16 [48][272] @ 0      (26,112)  x tile incl. 16-row causal halo
//   As    bf16 2x[32][136] @26,112 (17,408) A chunk dbuf
//   wts_s f32  [32][12]  @ 43,520 ( 1,536)
//   psum  f32  [32][5]   @ 45,056 (   640)
//   psq   f32  [32][5]   @ 45,696 (   640)
//   muA   f32  [32]      @ 46,336   rsA f32 [32] @ 46,464
//   normed bf16 [32][264] @ 0     (16,896)  aliases xs after chunk loop

template<int K>
DEVI void conv_lds(const float* __restrict__ cw,          // [K][256] expert
                   const __hip_bfloat16* __restrict__ xs,
                   int tloc,
                   const float* __restrict__ wts_s, int e,
                   __hip_bfloat16* __restrict__ dst, int d_l, int d_g)
{
    float c[K];
#pragma unroll
    for (int j = 0; j < K; j++) c[j] = cw[j * 256 + d_g];
    float w[K - 1];
#pragma unroll
    for (int i = 0; i < K - 1; i++)
        w[i] = bf2f(xs[(16 + tloc - (K - 1) + i) * 272 + d_g]);
#pragma unroll
    for (int t = 0; t < 16; t++) {
        float nv = bf2f(xs[(16 + tloc + t) * 272 + d_g]);
        float s = nv * c[K - 1];
#pragma unroll
        for (int i = 0; i < K - 1; i++) s += w[i] * c[i];
        dst[(tloc + t) * 136 + d_l] = f2bf(s * wts_s[(tloc + t) * 12 + e]);
#pragma unroll
        for (int i = 0; i + 1 < K - 1; i++) w[i] = w[i + 1];
        w[K - 2] = nv;
    }
}

// M=32 x N=64(wave slice) x K=NKS*32; distance-1 prefetch (R2-proven shape)
template<int NKS>
DEVI void gemm_tile(const __hip_bfloat16* __restrict__ A, int astride,
                    const __hip_bfloat16* __restrict__ Bg, int bstride,
                    floatx4 (&acc)[2][4], int l16, int quad, int nsl)
{
    const __hip_bfloat16* a0p = A + l16 * astride + quad * 8;
    const __hip_bfloat16* a1p = a0p + 16 * astride;
    const __hip_bfloat16* bp  = Bg + (nsl + l16) * bstride + quad * 8;
    short8 a0 = *(const short8*)(a0p);
    short8 a1 = *(const short8*)(a1p);
    short8 b[4];
#pragma unroll
    for (int nt = 0; nt < 4; nt++)
        b[nt] = *(const short8*)(bp + nt * 16 * bstride);
#pragma unroll
    for (int ks = 0; ks < NKS; ks++) {
        short8 na0, na1, nb[4];
        if (ks < NKS - 1) {
            na0 = *(const short8*)(a0p + (ks + 1) * 32);
            na1 = *(const short8*)(a1p + (ks + 1) * 32);
#pragma unroll
            for (int nt = 0; nt < 4; nt++)
                nb[nt] = *(const short8*)(bp + nt * 16 * bstride + (ks + 1) * 32);
        }
#pragma unroll
        for (int nt = 0; nt < 4; nt++) {
            acc[0][nt] = __builtin_amdgcn_mfma_f32_16x16x32_bf16(a0, b[nt], acc[0][nt], 0, 0, 0);
            acc[1][nt] = __builtin_amdgcn_mfma_f32_16x16x32_bf16(a1, b[nt], acc[1][nt], 0, 0, 0);
        }
        if (ks < NKS - 1) {
            a0 = na0; a1 = na1;
#pragma unroll
            for (int nt = 0; nt < 4; nt++) b[nt] = nb[nt];
        }
    }
}

__global__ __launch_bounds__(256, 2) void fused_kernel(
    const float* __restrict__ x,
    const float* __restrict__ ck5, const float* __restrict__ ck9,
    const float* __restrict__ ck17,
    const float* __restrict__ rb,      // [12]
    const float* __restrict__ gmm, const float* __restrict__ bta,
    const float* __restrict__ outb,
    const __hip_bfloat16* __restrict__ projWT,
    const __hip_bfloat16* __restrict__ outWT,
    const __hip_bfloat16* __restrict__ projbT,
    const __hip_bfloat16* __restrict__ rWT,
    float* __restrict__ out)
{
    __shared__ __align__(16) char smem[46592];
    __hip_bfloat16* xs = (__hip_bfloat16*)smem;       // [48][272]
    __hip_bfloat16* As = (__hip_bfloat16*)(smem + 26112);  // 2 x [32][136]
    float* wts_s = (float*)(smem + 43520);
    float* psum  = (float*)(smem + 45056);
    float* psq   = (float*)(smem + 45696);
    float* muA   = (float*)(smem + 46336);
    float* rsA   = (float*)(smem + 46464);
    __hip_bfloat16* normed = (__hip_bfloat16*)smem;   // [32][264] later

    const int tid  = threadIdx.x;
    const int wave = tid >> 6;
    const int lane = tid & 63;
    const int quad = lane >> 4;
    const int l16  = lane & 15;
    const int nsl  = wave * 64;                // n-slice base
    const int m0   = blockIdx.x * 32;
    const int bb   = m0 >> 12;
    const int t0   = m0 & 4095;

    // ---- stage x tile rows t0-16..t0+31, fp32 -> bf16 (R2-proven) ----
    {
        const float* xb = x + (size_t)bb * 4096 * 256;
        for (int idx = tid; idx < 48 * 64; idx += 256) {
            int row = idx >> 6, c4 = (idx & 63) << 2;
            int gt = t0 - 16 + row;
            short4_t v = {0, 0, 0, 0};
            if (gt >= 0) {
                float4 f = *(const float4*)(xb + (size_t)gt * 256 + c4);
                v[0] = (short)bfbits(f.x); v[1] = (short)bfbits(f.y);
                v[2] = (short)bfbits(f.z); v[3] = (short)bfbits(f.w);
            }
            *(short4_t*)(xs + row * 272 + c4) = v;
        }
    }
    __syncthreads();

    // ---- router (waves 0,1): MFMA logits + shuffle softmax ----
    if (wave < 2) {
        floatx4 ra = {0.f, 0.f, 0.f, 0.f};
        const __hip_bfloat16* ap = xs + (16 + wave * 16 + l16) * 272 + quad * 8;
        const __hip_bfloat16* bp = rWT + l16 * 256 + quad * 8;
#pragma unroll
        for (int kk = 0; kk < 256; kk += 32)
            ra = __builtin_amdgcn_mfma_f32_16x16x32_bf16(
                *(const short8*)(ap + kk), *(const short8*)(bp + kk), ra, 0, 0, 0);
        float rbv = (l16 < 12) ? rb[l16] : 0.f;
#pragma unroll
        for (int r = 0; r < 4; r++) {
            float v = (l16 < 12) ? (ra[r] + rbv) : -1e30f;
            float mx = v;
            mx = fmaxf(mx, __shfl_xor(mx, 1));
            mx = fmaxf(mx, __shfl_xor(mx, 2));
            mx = fmaxf(mx, __shfl_xor(mx, 4));
            mx = fmaxf(mx, __shfl_xor(mx, 8));
            float ex = (l16 < 12) ? __expf(v - mx) : 0.f;
            float sm = ex;
            sm += __shfl_xor(sm, 1);
            sm += __shfl_xor(sm, 2);
            sm += __shfl_xor(sm, 4);
            sm += __shfl_xor(sm, 8);
            if (l16 < 12) wts_s[(wave * 16 + quad * 4 + r) * 12 + l16] = ex / sm;
        }
    }
    __syncthreads();

    // producer chunk: c<24: e=c>>1, h=c&1; c==24: bias chunk (A = router wts)
    auto produce = [&](int c) {
        __hip_bfloat16* dst = As + (c & 1) * (32 * 136);
        if (c == 24) {
            int t = tid >> 3, k4 = (tid & 7) * 4;
            short4_t v;
#pragma unroll
            for (int j = 0; j < 4; j++) {
                int k = k4 + j;
                v[j] = (k < 12) ? (short)bfbits(wts_s[t * 12 + k]) : (short)0;
            }
            *(short4_t*)(dst + t * 136 + k4) = v;
        } else {
            int e = c >> 1, h = c & 1;
            int d_l = tid & 127, tloc = (tid >> 7) * 16;
            int d_g = h * 128 + d_l;
            if (e < 4)
                conv_lds<5>(ck5 + e * 5 * 256, xs, tloc, wts_s, e, dst, d_l, d_g);
            else if (e < 8)
                conv_lds<9>(ck9 + (e - 4) * 9 * 256, xs, tloc, wts_s, e, dst, d_l, d_g);
            else
                conv_lds<17>(ck17 + (e - 8) * 17 * 256, xs, tloc, wts_s, e, dst, d_l, d_g);
        }
    };

    floatx4 acc[2][4];
#pragma unroll
    for (int i = 0; i < 2; i++)
#pragma unroll
        for (int j = 0; j < 4; j++) acc[i][j] = {0.f, 0.f, 0.f, 0.f};

    produce(0);
    __syncthreads();

#pragma unroll 1
    for (int c = 0; c < 25; c++) {
        if (c < 24) {
            produce(c + 1);
            int e = c >> 1, h = c & 1;
            gemm_tile<4>(As + (c & 1) * (32 * 136), 136,
                         projWT + (e << 16) + h * 128, 256, acc, l16, quad, nsl);
        } else {
            gemm_tile<1>(As + (c & 1) * (32 * 136), 136,
                         projbT, 32, acc, l16, quad, nsl);
        }
        __syncthreads();
    }

    // ---- LN stats from accumulators (exact fp32) ----
    {
        float s[8], s2[8];
#pragma unroll
        for (int mf = 0; mf < 2; mf++)
#pragma unroll
            for (int r = 0; r < 4; r++) {
                int i = mf * 4 + r;
                float v = 0.f, q = 0.f;
#pragma unroll
                for (int nt = 0; nt < 4; nt++) {
                    float a = acc[mf][nt][r];
                    v += a; q += a * a;
                }
                s[i] = v; s2[i] = q;
            }
#pragma unroll
        for (int m = 1; m <= 8; m <<= 1)
#pragma unroll
            for (int i = 0; i < 8; i++) {
                s[i]  += __shfl_xor(s[i], m);
                s2[i] += __shfl_xor(s2[i], m);
            }
#pragma unroll
        for (int i = 0; i < 8; i++)
            if (l16 == i) {
                int row = (i >> 2) * 16 + quad * 4 + (i & 3);
                psum[row * 5 + wave] = s[i];
                psq[row * 5 + wave]  = s2[i];
            }
    }
    __syncthreads();
    if (tid < 32) {
        float ss = 0.f, qq = 0.f;
#pragma unroll
        for (int p = 0; p < 4; p++) { ss += psum[tid * 5 + p]; qq += psq[tid * 5 + p]; }
        float mu = ss * 0.00390625f;
        float var = fmaxf(qq * 0.00390625f - mu * mu, 0.f);
        muA[tid] = mu;
        rsA[tid] = rsqrtf(var + 1e-5f);
    }
    __syncthreads();

    // ---- normalize acc -> normed bf16 [32][264] (aliases xs) ----
#pragma unroll
    for (int nt = 0; nt < 4; nt++) {
        int col = nsl + nt * 16 + l16;
        float g = gmm[col], bt = bta[col];
#pragma unroll
        for (int mf = 0; mf < 2; mf++)
#pragma unroll
            for (int r = 0; r < 4; r++) {
                int row = mf * 16 + quad * 4 + r;
                normed[row * 264 + col] =
                    f2bf((acc[mf][nt][r] - muA[row]) * rsA[row] * g + bt);
            }
    }
    __syncthreads();

    // ---- out = normed @ out_W + out_b ----
    floatx4 acc2[2][4];
#pragma unroll
    for (int i = 0; i < 2; i++)
#pragma unroll
        for (int j = 0; j < 4; j++) acc2[i][j] = {0.f, 0.f, 0.f, 0.f};
    gemm_tile<8>(normed, 264, outWT, 256, acc2, l16, quad, nsl);

    float* op = out + (size_t)m0 * 256;
#pragma unroll
    for (int nt = 0; nt < 4; nt++) {
        int col = nsl + nt * 16 + l16;
        float ob = outb[col];
#pragma unroll
        for (int mf = 0; mf < 2; mf++)
#pragma unroll
            for (int r = 0; r < 4; r++) {
                int row = mf * 16 + quad * 4 + r;
                op[row * 256 + col] = acc2[mf][nt][r] + ob;
            }
    }
}

// -------------------------------------------------------------- launch ----
extern "C" void kernel_launch(void* const* d_in, const int* in_sizes, int n_in,
                              void* d_out, int out_size, void* d_ws, size_t ws_size,
                              hipStream_t stream)
{
    (void)in_sizes; (void)n_in; (void)out_size; (void)ws_size;
    const float* x     = (const float*)d_in[0];
    const float* ck5   = (const float*)d_in[1];
    const float* ck9   = (const float*)d_in[2];
    const float* ck17  = (const float*)d_in[3];
    const float* projW = (const float*)d_in[4];
    const float* projb = (const float*)d_in[5];
    const float* rW    = (const float*)d_in[6];
    const float* rb    = (const float*)d_in[7];
    const float* outW  = (const float*)d_in[8];
    const float* outb  = (const float*)d_in[9];
    const float* gmm   = (const float*)d_in[10];
    const float* bta   = (const float*)d_in[11];

    __hip_bfloat16* projWT = (__hip_bfloat16*)d_ws;
    __hip_bfloat16* outWT  = (__hip_bfloat16*)((char*)d_ws + 1572864);
    __hip_bfloat16* projbT = (__hip_bfloat16*)((char*)d_ws + 1703936);
    __hip_bfloat16* rWT    = (__hip_bfloat16*)((char*)d_ws + 1720320);

    prep_kernel<<<dim3(209), dim3(256), 0, stream>>>(
        rW, projW, outW, projb, projWT, outWT, projbT, rWT);
    fused_kernel<<<dim3(512), dim3(256), 0, stream>>>(
        x, ck5, ck9, ck17, rb, gmm, bta, outb,
        projWT, outWT, projbT, rWT, (float*)d_out);
}